// Round 7
// baseline (1928.388 us; speedup 1.0000x reference)
//
#include <hip/hip_runtime.h>

#define B_  64
#define T_  512
#define D_  64
#define U_  256
#define G4  1024   // 4*U
#define NT  512    // 8 waves, 2 per SIMD (forced by static LDS > 80 KB)

// U storage split per 16-col group: 9 cols in AGPRs (144 a-regs, inline-asm
// managed), 4 cols in arch VGPRs (64 v-regs, named ux16 SSA), 3 cols in LDS.
// LDS-U geometry (measured conflict-free in round 3): region R = g + 64*jj
// (jj-major => odd g-multiplier), stride 132 u32.
#define NREGC 13
#define LDSU_STRIDE 132                       // u32; 528 B, 16B-aligned

typedef _Float16 f16x2 __attribute__((ext_vector_type(2)));
typedef unsigned int ux16 __attribute__((ext_vector_type(16)));
union U32H2 { unsigned int u; f16x2 h; unsigned short s[2]; };

__device__ __forceinline__ float dot2(unsigned int a, unsigned int b, float c) {
    U32H2 ua, ub; ua.u = a; ub.u = b;
#if __has_builtin(__builtin_amdgcn_fdot2)
    return __builtin_amdgcn_fdot2(ua.h, ub.h, c, false);
#else
    return c + (float)ua.h.x * (float)ub.h.x + (float)ua.h.y * (float)ub.h.y;
#endif
}

template <int CTRL>
__device__ __forceinline__ float dpp_mov_f32(float x) {
    int m = __builtin_amdgcn_update_dpp(0, __float_as_int(x), CTRL, 0xF, 0xF, true);
    return __int_as_float(m);
}

__device__ __forceinline__ float sigmoidf_(float z) {
    return 1.f / (1.f + __expf(-z));
}

// ---------------------------------------------------------------------------
// Kernel 1: xz[t*B+b][g] = bias[g] + sum_d x[b][t][d] * W[d][g]   (fp32 exact)
// ---------------------------------------------------------------------------
__global__ __launch_bounds__(256) void xz_kernel(const float* __restrict__ x,
                                                 const float* __restrict__ W,
                                                 const float* __restrict__ bias,
                                                 float* __restrict__ xz) {
    __shared__ float xt[16][D_];
    const int g    = blockIdx.x * 256 + threadIdx.x;
    const int row0 = blockIdx.y * 16;

    #pragma unroll
    for (int j = 0; j < 4; ++j) {
        int e = threadIdx.x + 256 * j;
        int r = e >> 6, d = e & 63;
        int row = row0 + r;
        int t = row >> 6, b = row & 63;         // row = t*64 + b
        xt[r][d] = x[((size_t)b * T_ + t) * D_ + d];
    }
    __syncthreads();

    float acc[16];
    #pragma unroll
    for (int r = 0; r < 16; ++r) acc[r] = 0.f;

    for (int d = 0; d < D_; ++d) {
        float w = W[(size_t)d * G4 + g];
        #pragma unroll
        for (int r = 0; r < 16; ++r) acc[r] += xt[r][d] * w;
    }

    float bg = bias[g];
    #pragma unroll
    for (int r = 0; r < 16; ++r)
        xz[(size_t)(row0 + r) * G4 + g] = acc[r] + bg;
}

// ---------------------------------------------------------------------------
// Kernel 2: sequential scan, one WG (512 thr) per batch element.
// thread tau = (g = tau>>3, r = tau&7). Group g owns cols 16g..16g+15; slice r
// owns pairs [16r,16r+16) (k = 32r..32r+31).
// ---------------------------------------------------------------------------

struct LstmSmem {
    unsigned int  lds_u[192 * LDSU_STRIDE];   // 101376 B
    unsigned short h16[8 * 40];               // 8 slices x 80 B = 640 B
    float          z[G4];                     // 4096 B
    float          pd[U_];                    // 1024 B
};                                            // total 107136 B (< 163840)

// pack U[2*(16r+p)][col], U[2*(16r+p)+1][col] -> u32 of 2 f16
#define PACKP(p_) __extension__ ({                                            \
    U32H2 a_;                                                                 \
    a_.h = f16x2{(_Float16)Um[(size_t)(2 * (16 * r + (p_))) * G4 + col],      \
                 (_Float16)Um[(size_t)(2 * (16 * r + (p_)) + 1) * G4 + col]}; \
    a_.u; })

// ---- AGPR-resident U: 9 cols x 16 pairs = 144 named "a"-class variables ----
#define AG_DECL_J(j)                                                          \
    unsigned int aU_##j##_0_0, aU_##j##_0_1, aU_##j##_0_2, aU_##j##_0_3,      \
                 aU_##j##_1_0, aU_##j##_1_1, aU_##j##_1_2, aU_##j##_1_3,      \
                 aU_##j##_2_0, aU_##j##_2_1, aU_##j##_2_2, aU_##j##_2_3,      \
                 aU_##j##_3_0, aU_##j##_3_1, aU_##j##_3_2, aU_##j##_3_3;

#define AW1(j, I, e, p_)                                                      \
    asm volatile("v_accvgpr_write_b32 %0, %1"                                 \
                 : "=a"(aU_##j##_##I##_##e) : "v"(PACKP(p_)));

#define AG_INIT_J(j) {                                                        \
    const int col = 16 * g + (j);                                             \
    AW1(j,0,0,0)  AW1(j,0,1,1)  AW1(j,0,2,2)  AW1(j,0,3,3)                    \
    AW1(j,1,0,4)  AW1(j,1,1,5)  AW1(j,1,2,6)  AW1(j,1,3,7)                    \
    AW1(j,2,0,8)  AW1(j,2,1,9)  AW1(j,2,2,10) AW1(j,2,3,11)                   \
    AW1(j,3,0,12) AW1(j,3,1,13) AW1(j,3,2,14) AW1(j,3,3,15)                   \
    __builtin_amdgcn_sched_barrier(0); }

#define ARD(j, I, e) __extension__ ({                                         \
    unsigned int _r;                                                          \
    asm volatile("v_accvgpr_read_b32 %0, %1"                                  \
                 : "=v"(_r) : "a"(aU_##j##_##I##_##e));                       \
    _r; })

#define ADOT(j, I) {                                                          \
    acc##j = dot2(ARD(j,I,0), hp0, acc##j);                                   \
    acc##j = dot2(ARD(j,I,1), hp1, acc##j);                                   \
    acc##j = dot2(ARD(j,I,2), hp2, acc##j);                                   \
    acc##j = dot2(ARD(j,I,3), hp3, acc##j); }

#define INIT_UCOL(UV, jj) {                                   \
    const int col = 16 * g + (jj);                            \
    UV.s0 = PACKP(0);  UV.s1 = PACKP(1);  UV.s2 = PACKP(2);   \
    UV.s3 = PACKP(3);  UV.s4 = PACKP(4);  UV.s5 = PACKP(5);   \
    UV.s6 = PACKP(6);  UV.s7 = PACKP(7);  UV.s8 = PACKP(8);   \
    UV.s9 = PACKP(9);  UV.sa = PACKP(10); UV.sb = PACKP(11);  \
    UV.sc = PACKP(12); UV.sd = PACKP(13); UV.se = PACKP(14);  \
    UV.sf = PACKP(15);                                        \
    __builtin_amdgcn_sched_barrier(0); }

#define DOTC(UV, ACC, S0, S1, S2, S3) {      \
    ACC = dot2(UV.S0, hp0, ACC);             \
    ACC = dot2(UV.S1, hp1, ACC);             \
    ACC = dot2(UV.S2, hp2, ACC);             \
    ACC = dot2(UV.S3, hp3, ACC); }

#define DOTQ(Q, ACC) {                       \
    ACC = dot2(Q.x, hp0, ACC);               \
    ACC = dot2(Q.y, hp1, ACC);               \
    ACC = dot2(Q.z, hp2, ACC);               \
    ACC = dot2(Q.w, hp3, ACC); }

#define DOT_CHUNK(I, S0, S1, S2, S3) {                                  \
    const uint4 h4 = hq[I];                                             \
    const unsigned int hp0 = h4.x, hp1 = h4.y, hp2 = h4.z, hp3 = h4.w;  \
    ADOT(0, I) ADOT(1, I) ADOT(2, I) ADOT(3, I) ADOT(4, I)              \
    ADOT(5, I) ADOT(6, I) ADOT(7, I) ADOT(8, I)                         \
    DOTC(u9,  acc9,  S0, S1, S2, S3)                                    \
    DOTC(u10, acc10, S0, S1, S2, S3)                                    \
    DOTC(u11, acc11, S0, S1, S2, S3)                                    \
    DOTC(u12, acc12, S0, S1, S2, S3)                                    \
    { const uint4 q = lu0[I]; DOTQ(q, acc13) }                          \
    { const uint4 q = lu1[I]; DOTQ(q, acc14) }                          \
    { const uint4 q = lu2[I]; DOTQ(q, acc15) } }

#define RED(ACC) {                          \
    ACC += dpp_mov_f32<0xB1>(ACC);          \
    ACC += dpp_mov_f32<0x4E>(ACC);          \
    ACC += dpp_mov_f32<0x141>(ACC); }

__global__
__attribute__((amdgpu_flat_work_group_size(NT, NT), amdgpu_waves_per_eu(2, 2)))
void lstm_kernel(
        const float* __restrict__ Um,
        const float* __restrict__ dw,
        const float* __restrict__ dbp,
        const float* __restrict__ xz,
        float* __restrict__ out) {
    __shared__ LstmSmem sm;

    const int tau = threadIdx.x;
    const int b   = blockIdx.x;
    const int g   = tau >> 3;
    const int r   = tau & 7;

    // ---- one-time: AGPR-resident U (cols j=0..8 of group g) ----
    AG_DECL_J(0) AG_DECL_J(1) AG_DECL_J(2) AG_DECL_J(3) AG_DECL_J(4)
    AG_DECL_J(5) AG_DECL_J(6) AG_DECL_J(7) AG_DECL_J(8)
    AG_INIT_J(0) AG_INIT_J(1) AG_INIT_J(2) AG_INIT_J(3) AG_INIT_J(4)
    AG_INIT_J(5) AG_INIT_J(6) AG_INIT_J(7) AG_INIT_J(8)

    // ---- one-time: arch-VGPR-resident U (cols j=9..12) ----
    ux16 u9, u10, u11, u12;
    INIT_UCOL(u9, 9) INIT_UCOL(u10, 10) INIT_UCOL(u11, 11) INIT_UCOL(u12, 12)

    // ---- one-time: LDS-resident U cols 13..15. Region R = g + 64*jj ----
    for (int idx = tau; idx < 192 * 128; idx += NT) {
        const int R = idx >> 7, p = idx & 127;
        const int gg = R & 63, jj = R >> 6;
        const int col = 16 * gg + NREGC + jj;
        U32H2 a;
        a.h = f16x2{(_Float16)Um[(size_t)(2 * p) * G4 + col],
                    (_Float16)Um[(size_t)(2 * p + 1) * G4 + col]};
        sm.lds_u[R * LDSU_STRIDE + p] = a.u;
    }
    // ---- init h = 0 ----
    if (tau < U_) sm.h16[(tau >> 5) * 40 + (tau & 31)] = 0;

    const float dwr = (tau < U_) ? dw[tau] : 0.f;
    const float db0 = dbp[0];
    float c_state = 0.f;

    // per-thread LDS read bases
    const uint4* lu0 = (const uint4*)&sm.lds_u[(g +   0) * LDSU_STRIDE + 16 * r];
    const uint4* lu1 = (const uint4*)&sm.lds_u[(g +  64) * LDSU_STRIDE + 16 * r];
    const uint4* lu2 = (const uint4*)&sm.lds_u[(g + 128) * LDSU_STRIDE + 16 * r];
    const uint4* hq  = (const uint4*)((const char*)sm.h16 + r * 80);
    const int c2 = 16 * g + 2 * r;              // the two z columns this thread owns

    float2 xzc = *(const float2*)(xz + (size_t)b * G4 + c2);   // t=0
    __syncthreads();

    for (int t = 0; t < T_; ++t) {
        // prefetch next step's xz (hides L2/L3 latency under the dot phase)
        const int tn = (t + 1 < T_) ? t + 1 : t;
        const float2 xzn = *(const float2*)(xz + ((size_t)tn * B_ + b) * G4 + c2);

        // ---- partial dots over this slice's 32 k values, 16 columns ----
        float acc0 = 0.f, acc1 = 0.f, acc2 = 0.f, acc3 = 0.f;
        float acc4 = 0.f, acc5 = 0.f, acc6 = 0.f, acc7 = 0.f;
        float acc8 = 0.f, acc9 = 0.f, acc10 = 0.f, acc11 = 0.f;
        float acc12 = 0.f, acc13 = 0.f, acc14 = 0.f, acc15 = 0.f;

        DOT_CHUNK(0, s0, s1, s2, s3)
        DOT_CHUNK(1, s4, s5, s6, s7)
        DOT_CHUNK(2, s8, s9, sa, sb)
        DOT_CHUNK(3, sc, sd, se, sf)

        // ---- 8-lane butterfly reduce on the VALU/DPP pipe ----
        RED(acc0)  RED(acc1)  RED(acc2)  RED(acc3)
        RED(acc4)  RED(acc5)  RED(acc6)  RED(acc7)
        RED(acc8)  RED(acc9)  RED(acc10) RED(acc11)
        RED(acc12) RED(acc13) RED(acc14) RED(acc15)

        // lane r keeps columns 2r, 2r+1
        float z0 = acc0, z1 = acc1;
        if (r == 1) { z0 = acc2;  z1 = acc3;  }
        if (r == 2) { z0 = acc4;  z1 = acc5;  }
        if (r == 3) { z0 = acc6;  z1 = acc7;  }
        if (r == 4) { z0 = acc8;  z1 = acc9;  }
        if (r == 5) { z0 = acc10; z1 = acc11; }
        if (r == 6) { z0 = acc12; z1 = acc13; }
        if (r == 7) { z0 = acc14; z1 = acc15; }
        z0 += xzc.x;
        z1 += xzc.y;
        *(float2*)(sm.z + c2) = float2{z0, z1};
        __syncthreads();                        // z ready

        // ---- gates + state update (threads tau < 256, u = tau) ----
        if (tau < U_) {
            const int u = tau;
            float zi = sm.z[u];
            float zf = sm.z[U_ + u];
            float zg = sm.z[2 * U_ + u];
            float zo = sm.z[3 * U_ + u];
            float ig = sigmoidf_(zi);
            float fg = sigmoidf_(zf);
            float gg = fmaxf(zg, 0.f);
            float og = sigmoidf_(zo);
            c_state = fg * c_state + ig * gg;
            float h = og * fmaxf(c_state, 0.f);
            U32H2 hb; hb.h = f16x2{(_Float16)h, (_Float16)h};
            sm.h16[(u >> 5) * 40 + (u & 31)] = hb.s[0];
            sm.pd[u] = h * dwr;
        }
        __syncthreads();                        // h (and pd) ready

        // ---- dense: sigma[b][t] = sum_u h[u]*dw[u] + db ----
        if (tau < 64) {
            float s = sm.pd[tau] + sm.pd[tau + 64] + sm.pd[tau + 128] + sm.pd[tau + 192];
            #pragma unroll
            for (int off = 32; off > 0; off >>= 1)
                s += __shfl_down(s, off);
            if (tau == 0) out[(size_t)b * T_ + t] = s + db0;
        }

        xzc = xzn;
    }
}

// ---------------------------------------------------------------------------
// Fallback (no workspace): streaming kernel, correctness only.
// ---------------------------------------------------------------------------
__global__ __launch_bounds__(1024) void lstm_fallback(
        const float* __restrict__ x,  const float* __restrict__ W,
        const float* __restrict__ Um, const float* __restrict__ bias,
        const float* __restrict__ dw, const float* __restrict__ dbp,
        float* __restrict__ out) {
    __shared__ float h_s[U_];
    __shared__ float z_s2[G4];
    __shared__ float pd_s2[U_];
    const int g = threadIdx.x;
    const int b = blockIdx.x;
    const float bg  = bias[g];
    const float dwr = (g < U_) ? dw[g] : 0.f;
    const float db0 = dbp[0];
    float c = 0.f;
    if (g < U_) h_s[g] = 0.f;
    __syncthreads();
    const float* Ucol = Um + g;
    for (int t = 0; t < T_; ++t) {
        float acc = bg;
        const float* xrow = x + ((size_t)b * T_ + t) * D_;
        for (int d = 0; d < D_; ++d) acc += xrow[d] * W[(size_t)d * G4 + g];
        for (int k = 0; k < U_; ++k) acc += h_s[k] * Ucol[(size_t)k * G4];
        z_s2[g] = acc;
        __syncthreads();
        if (g < U_) {
            float ig = sigmoidf_(z_s2[g]);
            float fg = sigmoidf_(z_s2[U_ + g]);
            float gg = fmaxf(z_s2[2 * U_ + g], 0.f);
            float og = sigmoidf_(z_s2[3 * U_ + g]);
            c = fg * c + ig * gg;
            float h = og * fmaxf(c, 0.f);
            h_s[g] = h; pd_s2[g] = h * dwr;
        }
        __syncthreads();
        if (g < 64) {
            float s = pd_s2[g] + pd_s2[g + 64] + pd_s2[g + 128] + pd_s2[g + 192];
            #pragma unroll
            for (int off = 32; off > 0; off >>= 1) s += __shfl_down(s, off);
            if (g == 0) out[(size_t)b * T_ + t] = s + db0;
        }
        __syncthreads();
    }
}

// ---------------------------------------------------------------------------
extern "C" void kernel_launch(void* const* d_in, const int* in_sizes, int n_in,
                              void* d_out, int out_size, void* d_ws, size_t ws_size,
                              hipStream_t stream) {
    const float* x    = (const float*)d_in[0];
    const float* W    = (const float*)d_in[1];
    const float* Um   = (const float*)d_in[2];
    const float* bias = (const float*)d_in[3];
    const float* dw   = (const float*)d_in[4];
    const float* db   = (const float*)d_in[5];
    float* out = (float*)d_out;

    const size_t need = (size_t)T_ * B_ * G4 * sizeof(float);   // 128 MiB
    if (ws_size >= need) {
        float* xz = (float*)d_ws;
        dim3 gridX(G4 / 256, (T_ * B_) / 16);
        xz_kernel<<<gridX, 256, 0, stream>>>(x, W, bias, xz);
        lstm_kernel<<<B_, NT, 0, stream>>>(Um, dw, db, xz, out);
    } else {
        lstm_fallback<<<B_, 1024, 0, stream>>>(x, W, Um, bias, dw, db, out);
    }
}

// Round 9
// 936.557 us; speedup vs baseline: 2.0590x; 2.0590x over previous
//
#include <hip/hip_runtime.h>

#define B_  64
#define T_  512
#define D_  64
#define U_  256
#define G4  1024   // 4*U
#define NT  512    // 8 waves, 2 per SIMD

typedef _Float16 f16x8 __attribute__((ext_vector_type(8)));   // 16 B = 4 regs
typedef float    f32x4 __attribute__((ext_vector_type(4)));

__device__ __forceinline__ float sigmoidf_(float z) {
    return 1.f / (1.f + __expf(-z));
}

// ---------------------------------------------------------------------------
// Kernel 1: xz[t*B+b][g] = bias[g] + sum_d x[b][t][d] * W[d][g]   (fp32 exact)
// ---------------------------------------------------------------------------
__global__ __launch_bounds__(256) void xz_kernel(const float* __restrict__ x,
                                                 const float* __restrict__ W,
                                                 const float* __restrict__ bias,
                                                 float* __restrict__ xz) {
    __shared__ float xt[16][D_];
    const int g    = blockIdx.x * 256 + threadIdx.x;
    const int row0 = blockIdx.y * 16;

    #pragma unroll
    for (int j = 0; j < 4; ++j) {
        int e = threadIdx.x + 256 * j;
        int r = e >> 6, d = e & 63;
        int row = row0 + r;
        int t = row >> 6, bb = row & 63;        // row = t*64 + b
        xt[r][d] = x[((size_t)bb * T_ + t) * D_ + d];
    }
    __syncthreads();

    float acc[16];
    #pragma unroll
    for (int r = 0; r < 16; ++r) acc[r] = 0.f;

    for (int d = 0; d < D_; ++d) {
        float wv = W[(size_t)d * G4 + g];
        #pragma unroll
        for (int r = 0; r < 16; ++r) acc[r] += xt[r][d] * wv;
    }

    float bg = bias[g];
    #pragma unroll
    for (int r = 0; r < 16; ++r)
        xz[(size_t)(row0 + r) * G4 + g] = acc[r] + bg;
}

// ---------------------------------------------------------------------------
// Kernel 2: MFMA LSTM scan (intrinsics only, no inline asm).
// One WG (512 thr, 8 waves) per batch element. Wave w owns cols [128w,128w+128).
// z[1x1024] = h[1x256] @ U[256x1024] via __builtin_amdgcn_mfma_f32_16x16x32_f16:
//   A = h broadcast to all 16 rows (every lane in k-group gg supplies the same
//       h values -> all A rows equal -> all D rows equal).
//   B = U frags: 47/wave held in named f16x8 SSA values (unified-file RA
//       places them in AGPRs; MFMA reads AGPR operands natively),
//       17/wave in LDS (conflict-free 16B/lane reads).
// A and B use the SAME (k-group, element)->k load pattern, so the result is
// invariant to the hardware's internal k mapping (m97-verified property).
// ---------------------------------------------------------------------------

struct Smem {
    _Float16 h16[256];          // 512 B
    float    z[G4];             // 4 KB
    float    pd[U_];            // 1 KB
    f16x8    bl[8][17][64];     // 8 waves x 17 frags x 64 lanes x 16 B = 136 KB
};                              // total 144896 B  (< 163840)

// B frag element: lane (gg, li), elem e -> U[32*kt + 8*gg + e][16*ntg + li]
__device__ __forceinline__ f16x8 load_bfrag(const float* __restrict__ Um,
                                            int ntg, int kt, int gg, int li) {
    const float* p = Um + (size_t)(32 * kt + 8 * gg) * G4 + 16 * ntg + li;
    f16x8 v;
    #pragma unroll
    for (int e = 0; e < 8; ++e) v[e] = (_Float16)p[(size_t)e * G4];
    return v;
}

// ---- 47 register-resident B frags: kt=2 nt=1..7, kt=3..7 nt=0..7 ----
#define FOR_AG(X) \
    X(2,1) X(2,2) X(2,3) X(2,4) X(2,5) X(2,6) X(2,7) \
    X(3,0) X(3,1) X(3,2) X(3,3) X(3,4) X(3,5) X(3,6) X(3,7) \
    X(4,0) X(4,1) X(4,2) X(4,3) X(4,4) X(4,5) X(4,6) X(4,7) \
    X(5,0) X(5,1) X(5,2) X(5,3) X(5,4) X(5,5) X(5,6) X(5,7) \
    X(6,0) X(6,1) X(6,2) X(6,3) X(6,4) X(6,5) X(6,6) X(6,7) \
    X(7,0) X(7,1) X(7,2) X(7,3) X(7,4) X(7,5) X(7,6) X(7,7)

#define DB(K,N) f16x8 bF_##K##_##N;
#define IB(K,N) bF_##K##_##N = load_bfrag(Um, w8 + (N), (K), gg, li);

#define MMV(N, BV) acc##N = __builtin_amdgcn_mfma_f32_16x16x32_f16(av, (BV), acc##N, 0, 0, 0);
#define MMR(K, N)  acc##N = __builtin_amdgcn_mfma_f32_16x16x32_f16(av, bF_##K##_##N, acc##N, 0, 0, 0);

#define MKLDS(KT, FB) { \
    f16x8 av = *(const f16x8*)&sm.h16[32 * (KT) + 8 * gg]; \
    { f16x8 bv = sm.bl[w][(FB)+0][lane]; MMV(0, bv) } \
    { f16x8 bv = sm.bl[w][(FB)+1][lane]; MMV(1, bv) } \
    { f16x8 bv = sm.bl[w][(FB)+2][lane]; MMV(2, bv) } \
    { f16x8 bv = sm.bl[w][(FB)+3][lane]; MMV(3, bv) } \
    { f16x8 bv = sm.bl[w][(FB)+4][lane]; MMV(4, bv) } \
    { f16x8 bv = sm.bl[w][(FB)+5][lane]; MMV(5, bv) } \
    { f16x8 bv = sm.bl[w][(FB)+6][lane]; MMV(6, bv) } \
    { f16x8 bv = sm.bl[w][(FB)+7][lane]; MMV(7, bv) } }

#define MKREG(KT) { \
    f16x8 av = *(const f16x8*)&sm.h16[32 * (KT) + 8 * gg]; \
    MMR(KT,0) MMR(KT,1) MMR(KT,2) MMR(KT,3) \
    MMR(KT,4) MMR(KT,5) MMR(KT,6) MMR(KT,7) }

__global__
__attribute__((amdgpu_flat_work_group_size(NT, NT), amdgpu_waves_per_eu(2, 2)))
void lstm_kernel(
        const float* __restrict__ Um,
        const float* __restrict__ dw,
        const float* __restrict__ dbp,
        const float* __restrict__ xz,
        float* __restrict__ out) {
    __shared__ Smem sm;

    const int tau  = threadIdx.x;
    const int b    = blockIdx.x;
    const int w    = tau >> 6;          // wave 0..7
    const int lane = tau & 63;
    const int gg   = (tau >> 4) & 3;    // 16-lane k-group
    const int li   = tau & 15;
    const int w8   = 8 * w;             // global N-tile base for this wave

    // ---- one-time: register-resident B frags (RA -> AGPRs) ----
    FOR_AG(DB)
    FOR_AG(IB)
    __builtin_amdgcn_sched_barrier(0);

    // ---- one-time: LDS B frags (f: 0..7 -> kt0, 8..15 -> kt1, 16 -> kt2 nt0)
    #pragma unroll
    for (int f = 0; f < 17; ++f) {
        const int kt = f >> 3, nt = f & 7;
        sm.bl[w][f][lane] = load_bfrag(Um, w8 + nt, kt, gg, li);
    }

    if (tau < U_) sm.h16[tau] = (_Float16)0.f;

    const float dwr = (tau < U_) ? dw[tau] : 0.f;
    const float db0 = dbp[0];
    float c_state = 0.f;

    // xz prefetch for t=0 (gate threads only)
    float xq0 = 0.f, xq1 = 0.f, xq2 = 0.f, xq3 = 0.f;
    if (tau < U_) {
        const float* xp = xz + (size_t)b * G4;
        xq0 = xp[tau]; xq1 = xp[U_ + tau]; xq2 = xp[2 * U_ + tau]; xq3 = xp[3 * U_ + tau];
    }
    __syncthreads();

    for (int t = 0; t < T_; ++t) {
        // ---- MFMA phase: z = h @ U for this wave's 128 cols ----
        f32x4 acc0 = {0.f,0.f,0.f,0.f}, acc1 = {0.f,0.f,0.f,0.f};
        f32x4 acc2 = {0.f,0.f,0.f,0.f}, acc3 = {0.f,0.f,0.f,0.f};
        f32x4 acc4 = {0.f,0.f,0.f,0.f}, acc5 = {0.f,0.f,0.f,0.f};
        f32x4 acc6 = {0.f,0.f,0.f,0.f}, acc7 = {0.f,0.f,0.f,0.f};

        MKLDS(0, 0)                      // kt=0, LDS frags 0..7
        MKLDS(1, 8)                      // kt=1, LDS frags 8..15
        {                                // kt=2: nt0 from LDS frag 16, nt1..7 reg
            f16x8 av = *(const f16x8*)&sm.h16[64 + 8 * gg];
            { f16x8 bv = sm.bl[w][16][lane]; MMV(0, bv) }
            MMR(2,1) MMR(2,2) MMR(2,3) MMR(2,4) MMR(2,5) MMR(2,6) MMR(2,7)
        }
        MKREG(3) MKREG(4) MKREG(5) MKREG(6) MKREG(7)

        // D rows all identical (A rows broadcast) -> lanes 0..15, elem .x
        if (lane < 16) {
            const int zb = 128 * w + lane;
            sm.z[zb]       = acc0.x;  sm.z[zb + 16]  = acc1.x;
            sm.z[zb + 32]  = acc2.x;  sm.z[zb + 48]  = acc3.x;
            sm.z[zb + 64]  = acc4.x;  sm.z[zb + 80]  = acc5.x;
            sm.z[zb + 96]  = acc6.x;  sm.z[zb + 112] = acc7.x;
        }
        __syncthreads();                 // z ready

        // ---- gates + state update (threads tau < 256, u = tau) ----
        if (tau < U_) {
            float zi = sm.z[tau]            + xq0;
            float zf = sm.z[U_ + tau]       + xq1;
            float zg = sm.z[2 * U_ + tau]   + xq2;
            float zo = sm.z[3 * U_ + tau]   + xq3;
            float ig = sigmoidf_(zi);
            float fg = sigmoidf_(zf);
            float gv = fmaxf(zg, 0.f);
            float og = sigmoidf_(zo);
            c_state = fg * c_state + ig * gv;
            float h = og * fmaxf(c_state, 0.f);
            sm.h16[tau] = (_Float16)h;
            sm.pd[tau]  = h * dwr;
            // prefetch next step's xz (hidden under next MFMA phase)
            const int tn = (t + 1 < T_) ? t + 1 : t;
            const float* xp = xz + ((size_t)tn * B_ + b) * G4;
            xq0 = xp[tau]; xq1 = xp[U_ + tau]; xq2 = xp[2 * U_ + tau]; xq3 = xp[3 * U_ + tau];
        }
        __syncthreads();                 // h, pd ready

        // ---- dense: sigma[b][t] = sum_u h[u]*dw[u] + db ----
        if (tau < 64) {
            float s = sm.pd[tau] + sm.pd[tau + 64] + sm.pd[tau + 128] + sm.pd[tau + 192];
            #pragma unroll
            for (int off = 32; off > 0; off >>= 1)
                s += __shfl_down(s, off);
            if (tau == 0) out[(size_t)b * T_ + t] = s + db0;
        }
    }
}

// ---------------------------------------------------------------------------
// Fallback (no workspace): streaming kernel, correctness only.
// ---------------------------------------------------------------------------
__global__ __launch_bounds__(1024) void lstm_fallback(
        const float* __restrict__ x,  const float* __restrict__ W,
        const float* __restrict__ Um, const float* __restrict__ bias,
        const float* __restrict__ dw, const float* __restrict__ dbp,
        float* __restrict__ out) {
    __shared__ float h_s[U_];
    __shared__ float z_s2[G4];
    __shared__ float pd_s2[U_];
    const int g = threadIdx.x;
    const int b = blockIdx.x;
    const float bg  = bias[g];
    const float dwr = (g < U_) ? dw[g] : 0.f;
    const float db0 = dbp[0];
    float c = 0.f;
    if (g < U_) h_s[g] = 0.f;
    __syncthreads();
    const float* Ucol = Um + g;
    for (int t = 0; t < T_; ++t) {
        float acc = bg;
        const float* xrow = x + ((size_t)b * T_ + t) * D_;
        for (int d = 0; d < D_; ++d) acc += xrow[d] * W[(size_t)d * G4 + g];
        for (int k = 0; k < U_; ++k) acc += h_s[k] * Ucol[(size_t)k * G4];
        z_s2[g] = acc;
        __syncthreads();
        if (g < U_) {
            float ig = sigmoidf_(z_s2[g]);
            float fg = sigmoidf_(z_s2[U_ + g]);
            float gg2 = fmaxf(z_s2[2 * U_ + g], 0.f);
            float og = sigmoidf_(z_s2[3 * U_ + g]);
            c = fg * c + ig * gg2;
            float h = og * fmaxf(c, 0.f);
            h_s[g] = h; pd_s2[g] = h * dwr;
        }
        __syncthreads();
        if (g < 64) {
            float s = pd_s2[g] + pd_s2[g + 64] + pd_s2[g + 128] + pd_s2[g + 192];
            #pragma unroll
            for (int off = 32; off > 0; off >>= 1) s += __shfl_down(s, off);
            if (g == 0) out[(size_t)b * T_ + t] = s + db0;
        }
        __syncthreads();
    }
}

// ---------------------------------------------------------------------------
extern "C" void kernel_launch(void* const* d_in, const int* in_sizes, int n_in,
                              void* d_out, int out_size, void* d_ws, size_t ws_size,
                              hipStream_t stream) {
    const float* x    = (const float*)d_in[0];
    const float* W    = (const float*)d_in[1];
    const float* Um   = (const float*)d_in[2];
    const float* bias = (const float*)d_in[3];
    const float* dw   = (const float*)d_in[4];
    const float* db   = (const float*)d_in[5];
    float* out = (float*)d_out;

    const size_t need = (size_t)T_ * B_ * G4 * sizeof(float);   // 128 MiB
    if (ws_size >= need) {
        float* xz = (float*)d_ws;
        dim3 gridX(G4 / 256, (T_ * B_) / 16);
        xz_kernel<<<gridX, 256, 0, stream>>>(x, W, bias, xz);
        lstm_kernel<<<B_, NT, 0, stream>>>(Um, dw, db, xz, out);
    } else {
        lstm_fallback<<<B_, 1024, 0, stream>>>(x, W, Um, bias, dw, db, out);
    }
}